// Round 2
// baseline (79.574 us; speedup 1.0000x reference)
//
#include <hip/hip_runtime.h>

// ConjunctionLayer: out[b,j] = -1 / (-1 + sum_i log(1 - (1-x[b,i]) * W[j,i]))
// B=4096, INPUT_DIM=512, N=128, fp32.
//
// R5: kill the broadcast-read bottleneck. R3b/R4 post-mortem: x is
// wave-uniform, and BOTH global-vector and LDS reads of it pay the full
// 64-lane return path (1024 B returned per 16 B useful): 272 ds_read_b128
// x 16 waves/CU x ~12 cyc ~= 22 us/CU — the real cost, vs ~5 us VALU.
// Fix: x goes through the SCALAR pipe.
//   * prep_kernel writes xm = x-1 into workspace (16 MB traffic, ~3 us),
//     so hot fma is z = fma(w, s_xm, 1.0) — inline-const 1.0, no u[] regs.
//   * hot loop reads xm via inline-asm s_load_dwordx16 into SGPRs (zero
//     vector-return BW, zero LDS). lgkmcnt(0) wait carries "+s" data deps
//     so the compiler cannot hoist uses above it (rule #18).
//   * W[j, k0:k0+64] per lane in 16 named v4f (64 VGPRs, SSA — no arrays).
//   * VGPR ~100 -> launch_bounds(512,4): 2 blocks/CU, 4 waves/SIMD; s_load
//     latency (~200 cyc) hides under 4 waves x ~210 cyc VALU per bi.
// Mapping unchanged: lane <-> j (64 j/wave, h = j-half), wave <-> K-chunk
// (8 waves x 64 i), 16 b per block; product-of-16 z -> one v_log_f32
// (z in (0.5,1] so partial product >= 0.5^16 stays normal fp32).

typedef float v4f  __attribute__((ext_vector_type(4)));
typedef float v16sf __attribute__((ext_vector_type(16)));

constexpr int IDIM  = 512;
constexpr int NOUT  = 128;
constexpr int BTOT  = 4096;
constexpr int KC    = 64;            // i per wave
constexpr int NB    = 16;            // b per block
constexpr int GB    = BTOT / NB;     // 256 b-groups
constexpr float LN2 = 0.69314718055994530942f;

// ---- pre-kernel: xm = x - 1 into workspace (coalesced dwordx4) ----
__global__ __launch_bounds__(256)
void prep_kernel(const float* __restrict__ x, float* __restrict__ xm)
{
    const int t = blockIdx.x * 256 + threadIdx.x;      // 0 .. 262143
    const v4f* xi = (const v4f*)x;
    v4f* xo = (v4f*)xm;
    v4f a = xi[t];
    v4f b = xi[t + 262144];
    xo[t]          = a - 1.0f;
    xo[t + 262144] = b - 1.0f;
}

// 64 floats of wave-uniform xm -> 4 x s_load_dwordx16 into SGPRs.
// Second asm ties the results as "+s" so every use data-depends on the
// lgkmcnt(0) wait (SMEM returns out of order; 0 is the only safe wait).
__device__ __forceinline__ void sload64(const float* base,
                                        v16sf& a, v16sf& b, v16sf& c, v16sf& d)
{
    asm volatile("s_load_dwordx16 %0, %4, 0x0\n\t"
                 "s_load_dwordx16 %1, %4, 0x40\n\t"
                 "s_load_dwordx16 %2, %4, 0x80\n\t"
                 "s_load_dwordx16 %3, %4, 0xc0"
                 : "=s"(a), "=s"(b), "=s"(c), "=s"(d)
                 : "s"(base));
    asm volatile("s_waitcnt lgkmcnt(0)"
                 : "+s"(a), "+s"(b), "+s"(c), "+s"(d));
}

// One v_log_f32 per 16 i. s = xm[b, i0:i0+16] in SGPRs; wa..wd = per-lane
// W[j, i0:i0+16] in VGPRs. z = fma(w, xm, 1.0): 1 SGPR + inline const.
__device__ __forceinline__ float grouplog(v16sf s,
                                          v4f wa, v4f wb, v4f wc, v4f wd)
{
    v4f t0 = {s[0],  s[1],  s[2],  s[3]};
    v4f t1 = {s[4],  s[5],  s[6],  s[7]};
    v4f t2 = {s[8],  s[9],  s[10], s[11]};
    v4f t3 = {s[12], s[13], s[14], s[15]};
    v4f z0 = wa * t0 + 1.0f;
    v4f z1 = wb * t1 + 1.0f;
    v4f z2 = wc * t2 + 1.0f;
    v4f z3 = wd * t3 + 1.0f;
    v4f p  = (z0 * z1) * (z2 * z3);
    float m = (p.x * p.y) * (p.z * p.w);
    return __builtin_amdgcn_logf(m);   // v_log_f32 (log2); rescale by ln2 at end
}

__global__ __launch_bounds__(512, 4)
void conj_kernel(const float* __restrict__ xm,
                 const float* __restrict__ W,
                 float* __restrict__ out)
{
    __shared__ __align__(16) float s_p[NB * 8 * 64];  // 32 KB: partial log-sums

    const int tid  = threadIdx.x;
    const int lane = tid & 63;
    const int wv   = __builtin_amdgcn_readfirstlane(tid >> 6);   // 0..7, SGPR
    const int h    = blockIdx.x >> 8;        // j-half; h-pairs 256 apart
    const int bg   = blockIdx.x & (GB - 1);
    const int b0   = bg * NB;
    const int j    = h * 64 + lane;
    const int k0   = wv * KC;

    // Loop-invariant W fragment: W[j, k0:k0+64] as 16 named v4f (64 VGPRs).
    const v4f* wp = (const v4f*)(W + (size_t)j * IDIM + k0);
    v4f w0  = wp[0],  w1  = wp[1],  w2  = wp[2],  w3  = wp[3];
    v4f w4  = wp[4],  w5  = wp[5],  w6  = wp[6],  w7  = wp[7];
    v4f w8  = wp[8],  w9  = wp[9],  w10 = wp[10], w11 = wp[11];
    v4f w12 = wp[12], w13 = wp[13], w14 = wp[14], w15 = wp[15];

    const float* xb = xm + (size_t)b0 * IDIM + k0;    // wave-uniform base

    for (int bi = 0; bi < NB; ++bi) {
        v16sf sA, sB, sC, sD;
        sload64(xb + (size_t)bi * IDIM, sA, sB, sC, sD);
        float s = grouplog(sA, w0,  w1,  w2,  w3)
                + grouplog(sB, w4,  w5,  w6,  w7)
                + grouplog(sC, w8,  w9,  w10, w11)
                + grouplog(sD, w12, w13, w14, w15);
        s_p[bi * 512 + wv * 64 + lane] = s;    // lanes consecutive: no conflict
    }
    __syncthreads();

    // Reduce the 8 K-chunks, finalize, coalesced store.
    #pragma unroll
    for (int r = 0; r < (NB * 64) / 512; ++r) {   // 2 outputs/thread
        const int idx = tid + r * 512;
        const int bi  = idx >> 6;
        const int l   = idx & 63;
        float sum = 0.0f;
        #pragma unroll
        for (int wq = 0; wq < 8; ++wq)
            sum += s_p[bi * 512 + wq * 64 + l];   // stride 64: conflict-free
        out[(size_t)(b0 + bi) * NOUT + h * 64 + l] = 1.0f / (1.0f - LN2 * sum);
    }
}

extern "C" void kernel_launch(void* const* d_in, const int* in_sizes, int n_in,
                              void* d_out, int out_size, void* d_ws, size_t ws_size,
                              hipStream_t stream) {
    const float* x = (const float*)d_in[0];   // (4096, 512) fp32
    const float* W = (const float*)d_in[1];   // (128, 512) fp32
    float* out = (float*)d_out;               // (4096, 128) fp32
    float* xm  = (float*)d_ws;                // workspace: x - 1 (8 MB)

    // prep: xm = x - 1  (1024 blocks x 256 thr, 2 x v4f each)
    hipLaunchKernelGGL(prep_kernel, dim3(1024), dim3(256), 0, stream, x, xm);
    // main
    hipLaunchKernelGGL(conj_kernel, dim3(2 * GB), dim3(512), 0, stream, xm, W, out);
}

// Round 4
// 76.586 us; speedup vs baseline: 1.0390x; 1.0390x over previous
//
#include <hip/hip_runtime.h>

// ConjunctionLayer: out[b,j] = -1 / (-1 + sum_i log(1 - (1-x[b,i]) * W[j,i]))
// B=4096, INPUT_DIM=512, N=128, fp32.
//
// R6b: resubmit of R6 (bench infra failed twice; kernel never ran).
// Occupancy attack. R3b/R4/R5 post-mortem: three different x-delivery
// paths (uniform global / LDS broadcast / SMEM s_load) all ~same time, so
// x-delivery is NOT the bottleneck. VALU issue floor is ~4-7 us but the
// kernel runs ~33 us at VALUBusy ~17% (prior session) -> latency-bound at
// <=16 waves/CU. The invariant blocker was the 64-VGPR W fragment pushing
// past the 85-reg threshold for 3 blocks/CU.
// Fix:
//   * Live-range-split W: hold 32 W VGPRs at a time (phase A: i in
//     [k0,k0+32), phase B: [k0+32,k0+64)); phase-B W reloaded from L2
//     (W is L2-resident; ~4 us chip-wide, overlapped). sched_barrier(0)
//     between phases so the compiler can't hoist phase-B loads back up.
//   * NB=8 b/block -> LDS 16 KB (xm tile) + 16 KB (partials) = 32 KB.
//   * Target ~75 VGPR -> __launch_bounds__(512,6): 3 blocks/CU,
//     24 waves/CU (6/SIMD), +50% latency hiding; 1024 blocks balance
//     dispatch better than 512.
//   * acc[8] indexed only by fully-unrolled bi (static indices, no scratch).
// Mapping: lane <-> j (64 j/wave, h = j-half), wave <-> 64-i chunk,
// 8 b per block; product-of-16 z -> one v_log_f32 (z in (0.5,1] so the
// partial product >= 0.5^16 stays normal fp32). z = fma(W, x-1, 1.0) with
// xm = x-1 computed during the LDS stage (free).

typedef float v4f __attribute__((ext_vector_type(4)));

constexpr int IDIM  = 512;
constexpr int NOUT  = 128;
constexpr int BTOT  = 4096;
constexpr int NB    = 8;             // b per block
constexpr int GB    = BTOT / NB;     // 512 b-groups
constexpr float LN2 = 0.69314718055994530942f;

// One v_log_f32 per 16 i. xq: wave-uniform LDS pointer to xm[b, i0:i0+16];
// wa..wd: per-lane W[j, i0:i0+16] in SSA regs.
__device__ __forceinline__ float grouplog(const v4f* __restrict__ xq,
                                          v4f wa, v4f wb, v4f wc, v4f wd) {
    v4f t0 = xq[0], t1 = xq[1], t2 = xq[2], t3 = xq[3];
    v4f z0 = wa * t0 + 1.0f;          // z = W*(x-1) + 1
    v4f z1 = wb * t1 + 1.0f;
    v4f z2 = wc * t2 + 1.0f;
    v4f z3 = wd * t3 + 1.0f;
    v4f p  = (z0 * z1) * (z2 * z3);
    float m = (p.x * p.y) * (p.z * p.w);
    return __builtin_amdgcn_logf(m);  // v_log_f32 (log2); rescale by ln2 at end
}

__global__ __launch_bounds__(512, 6)
void conj_kernel(const float* __restrict__ x,
                 const float* __restrict__ W,
                 float* __restrict__ out)
{
    __shared__ __align__(16) float s_xm[NB * IDIM];   // 16 KB: x-1 tile
    __shared__ __align__(16) float s_p[NB * 8 * 64];  // 16 KB: partial log-sums

    const int tid  = threadIdx.x;
    const int lane = tid & 63;
    const int wv   = __builtin_amdgcn_readfirstlane(tid >> 6);   // 0..7, SGPR
    const int h    = blockIdx.x & 1;          // j-half; same-bg pairs adjacent
    const int bg   = blockIdx.x >> 1;         // 0..511
    const int b0   = bg * NB;
    const int j    = h * 64 + lane;
    const int k0   = wv * 64;

    // Stage xm = x - 1 into LDS: 8 b x 512 i = 1024 v4f over 512 threads.
    {
        const v4f* xg = (const v4f*)(x + (size_t)b0 * IDIM);
        v4f* xs = (v4f*)s_xm;
        xs[tid]       = xg[tid]       - 1.0f;
        xs[tid + 512] = xg[tid + 512] - 1.0f;
    }
    __syncthreads();

    const v4f* wp = (const v4f*)(W + (size_t)j * IDIM + k0);
    float acc[NB];                    // static (unrolled) indexing only

    // ---- phase A: i in [k0, k0+32), W half #1 in 32 VGPRs ----
    {
        v4f w0 = wp[0], w1 = wp[1], w2 = wp[2], w3 = wp[3];
        v4f w4 = wp[4], w5 = wp[5], w6 = wp[6], w7 = wp[7];
        #pragma unroll
        for (int bi = 0; bi < NB; ++bi) {
            const v4f* xq = (const v4f*)(s_xm + bi * IDIM + k0);
            acc[bi] = grouplog(xq,     w0, w1, w2, w3)
                    + grouplog(xq + 4, w4, w5, w6, w7);
        }
    }
    __builtin_amdgcn_sched_barrier(0);   // keep phase-B W loads below here

    // ---- phase B: i in [k0+32, k0+64), W half #2 reuses the 32 VGPRs ----
    {
        v4f w0 = wp[8],  w1 = wp[9],  w2 = wp[10], w3 = wp[11];
        v4f w4 = wp[12], w5 = wp[13], w6 = wp[14], w7 = wp[15];
        #pragma unroll
        for (int bi = 0; bi < NB; ++bi) {
            const v4f* xq = (const v4f*)(s_xm + bi * IDIM + k0 + 32);
            acc[bi] += grouplog(xq,     w0, w1, w2, w3)
                     + grouplog(xq + 4, w4, w5, w6, w7);
        }
    }

    #pragma unroll
    for (int bi = 0; bi < NB; ++bi)
        s_p[bi * 512 + wv * 64 + lane] = acc[bi];   // lanes consecutive
    __syncthreads();

    // Reduce the 8 K-chunks, finalize, coalesced store: 1 output/thread.
    {
        const int bi = tid >> 6;
        const int l  = tid & 63;
        float sum = 0.0f;
        #pragma unroll
        for (int wq = 0; wq < 8; ++wq)
            sum += s_p[bi * 512 + wq * 64 + l];     // stride 64: conflict-free
        out[(size_t)(b0 + bi) * NOUT + h * 64 + l] = 1.0f / (1.0f - LN2 * sum);
    }
}

extern "C" void kernel_launch(void* const* d_in, const int* in_sizes, int n_in,
                              void* d_out, int out_size, void* d_ws, size_t ws_size,
                              hipStream_t stream) {
    const float* x = (const float*)d_in[0];   // (4096, 512) fp32
    const float* W = (const float*)d_in[1];   // (128, 512) fp32
    float* out = (float*)d_out;               // (4096, 128) fp32

    dim3 grid(2 * GB);                        // 1024 blocks (bg-major, h interleaved)
    dim3 block(512);                          // 8 waves
    hipLaunchKernelGGL(conj_kernel, grid, block, 0, stream, x, W, out);
}

// Round 6
// 73.627 us; speedup vs baseline: 1.0808x; 1.0402x over previous
//
#include <hip/hip_runtime.h>

// ConjunctionLayer: out[b,j] = -1 / (-1 + sum_i log(1 - (1-x[b,i]) * W[j,i]))
// B=4096, INPUT_DIM=512, N=128, fp32.
//
// R7b: resubmit of R7 (bench infra failed twice; kernel never ran).
// Kill the W-gather. Post-mortems: x-delivery (R3b/R4/R5) and
// occupancy (R6b) both falsified — all land 74.5-79.6 us. The untouched
// invariant: every wave loads W[j=lane, 64 i] with lanes 2048 B apart ->
// 64 cache-line transactions per instruction, ~16K TA-serialized cycles
// per CU (~7 us prologue occupancy can't hide). R6b's 2x gather traffic
// costing +2 us is the one positive signal for this term.
// Fix:
//   * W staged coalesced through LDS in 4 rounds of [64 rows][128 i]
//     (32 KB, aliased onto the s_p buffer): 32 lanes cover each 512-B
//     row-slice -> 16 lines/instr (4x fewer transactions). XOR swizzle
//     chunk ^ (row&7) keeps write side free and read side ~8-way on a
//     one-time cost (~0.6 K cyc). Wave wv's fragment: i = g*128+wv*16+[0,16)
//     per group g — still 16-contiguous, x pointers re-aimed to match.
//   * XCD pairing fixed: blockIdx swizzled so (bg,h=0) and (bg,h=1) share
//     a mod-8 class -> same XCD L2 serves both reads of the x tile
//     (R6b had them adjacent = different XCDs).
//   * Everything else = R4 (best measured): NB=16, 8 waves, lane<->j,
//     z = fma(W, x-1, 1.0), product-of-16 -> one v_log_f32, s_p reduce.
// Pre-commitment: |delta| < 2 us => declare roofline (41 us HBM-bound
// harness fill + kernel insensitive to every modeled lever).

typedef float v4f __attribute__((ext_vector_type(4)));

constexpr int IDIM  = 512;
constexpr int NOUT  = 128;
constexpr int BTOT  = 4096;
constexpr int NB    = 16;            // b per block
constexpr int GB    = BTOT / NB;     // 256 b-groups
constexpr float LN2 = 0.69314718055994530942f;

// One v_log_f32 per 16 i. xq: wave-uniform LDS pointer to xm[b, 16 i];
// wa..wd: per-lane W[j, same 16 i] in SSA regs. z = fma(W, x-1, 1.0).
__device__ __forceinline__ float grouplog(const v4f* __restrict__ xq,
                                          v4f wa, v4f wb, v4f wc, v4f wd) {
    v4f t0 = xq[0], t1 = xq[1], t2 = xq[2], t3 = xq[3];
    v4f z0 = wa * t0 + 1.0f;
    v4f z1 = wb * t1 + 1.0f;
    v4f z2 = wc * t2 + 1.0f;
    v4f z3 = wd * t3 + 1.0f;
    v4f p  = (z0 * z1) * (z2 * z3);
    float m = (p.x * p.y) * (p.z * p.w);
    return __builtin_amdgcn_logf(m);  // v_log_f32 (log2); rescale by ln2 at end
}

// Coalesced stage of W[jh+0..63][r*128 .. r*128+128) into s_b.
// 32 lanes cover one 512-B row-slice; 4 passes cover 64 rows.
// LDS layout: row*128 floats, 16-B chunk index XOR-swizzled by (row&7).
__device__ __forceinline__ void w_write(const float* __restrict__ W,
                                        float* __restrict__ s_b,
                                        int jh, int r, int srow, int sc) {
    #pragma unroll
    for (int p = 0; p < 4; ++p) {
        const int row = srow + p * 16;
        v4f t = *(const v4f*)(W + (size_t)(jh + row) * IDIM + r * 128 + sc * 4);
        *(v4f*)(s_b + row * 128 + ((sc ^ (row & 7)) * 4)) = t;
    }
}

// Read back this wave's fragment for round r: lane's own row, chunks
// wv*4+q (q=0..3), same XOR involution.
__device__ __forceinline__ void w_read(const float* __restrict__ s_b,
                                       int lane, int wv,
                                       v4f& a, v4f& b, v4f& c, v4f& d) {
    const int base = lane * 128;
    const int m = lane & 7;
    a = *(const v4f*)(s_b + base + (((wv * 4 + 0) ^ m) * 4));
    b = *(const v4f*)(s_b + base + (((wv * 4 + 1) ^ m) * 4));
    c = *(const v4f*)(s_b + base + (((wv * 4 + 2) ^ m) * 4));
    d = *(const v4f*)(s_b + base + (((wv * 4 + 3) ^ m) * 4));
}

__global__ __launch_bounds__(512, 4)
void conj_kernel(const float* __restrict__ x,
                 const float* __restrict__ W,
                 float* __restrict__ out)
{
    __shared__ __align__(16) float s_xm[NB * IDIM];   // 32 KB: x-1 tile
    __shared__ __align__(16) float s_b[NB * 512];     // 32 KB: W-stage, then partials

    const int tid  = threadIdx.x;
    const int lane = tid & 63;
    const int wv   = __builtin_amdgcn_readfirstlane(tid >> 6);   // 0..7

    // XCD-pairing swizzle: q -> (bg,h) with (bg,0),(bg,1) 8 apart (same
    // mod-8 class -> same XCD under round-robin dispatch).
    const int q  = blockIdx.x;                 // 0..511
    const int bg = ((q >> 4) << 3) + (q & 7);  // 0..255
    const int h  = (q >> 3) & 1;
    const int b0 = bg * NB;
    const int jh = h * 64;

    // ---- x stage: xm = x-1, 16 b x 512 i = 2048 v4f over 512 threads ----
    {
        const v4f* xg = (const v4f*)(x + (size_t)b0 * IDIM);
        v4f* xs = (v4f*)s_xm;
        #pragma unroll
        for (int p = 0; p < 4; ++p)
            xs[tid + p * 512] = xg[tid + p * 512] - 1.0f;
    }

    const int srow = tid >> 5;       // 0..15
    const int sc   = tid & 31;       // 16-B chunk within 512-B row-slice

    v4f w0,w1,w2,w3,w4,w5,w6,w7,w8,w9,w10,w11,w12,w13,w14,w15;

    w_write(W, s_b, jh, 0, srow, sc);
    __syncthreads();
    w_read(s_b, lane, wv, w0, w1, w2, w3);
    __syncthreads();
    w_write(W, s_b, jh, 1, srow, sc);
    __syncthreads();
    w_read(s_b, lane, wv, w4, w5, w6, w7);
    __syncthreads();
    w_write(W, s_b, jh, 2, srow, sc);
    __syncthreads();
    w_read(s_b, lane, wv, w8, w9, w10, w11);
    __syncthreads();
    w_write(W, s_b, jh, 3, srow, sc);
    __syncthreads();
    w_read(s_b, lane, wv, w12, w13, w14, w15);
    __syncthreads();                           // s_b free for reuse as s_p

    // ---- main loop: wave wv covers i in {g*128 + wv*16 + [0,16)} ----
    for (int bi = 0; bi < NB; ++bi) {
        const v4f* xb = (const v4f*)s_xm + bi * 128 + wv * 4;
        float s = grouplog(xb,      w0,  w1,  w2,  w3)
                + grouplog(xb + 32, w4,  w5,  w6,  w7)
                + grouplog(xb + 64, w8,  w9,  w10, w11)
                + grouplog(xb + 96, w12, w13, w14, w15);
        s_b[bi * 512 + wv * 64 + lane] = s;    // lanes consecutive: no conflict
    }
    __syncthreads();

    // ---- reduce 8 K-chunks, finalize, coalesced store: 2 outputs/thread ----
    #pragma unroll
    for (int r = 0; r < (NB * 64) / 512; ++r) {
        const int idx = tid + r * 512;
        const int bi  = idx >> 6;
        const int l   = idx & 63;
        float sum = 0.0f;
        #pragma unroll
        for (int wq = 0; wq < 8; ++wq)
            sum += s_b[bi * 512 + wq * 64 + l];   // stride 64: conflict-free
        out[(size_t)(b0 + bi) * NOUT + jh + l] = 1.0f / (1.0f - LN2 * sum);
    }
}

extern "C" void kernel_launch(void* const* d_in, const int* in_sizes, int n_in,
                              void* d_out, int out_size, void* d_ws, size_t ws_size,
                              hipStream_t stream) {
    const float* x = (const float*)d_in[0];   // (4096, 512) fp32
    const float* W = (const float*)d_in[1];   // (128, 512) fp32
    float* out = (float*)d_out;               // (4096, 128) fp32

    dim3 grid(2 * GB);                        // 512 blocks
    dim3 block(512);                          // 8 waves
    hipLaunchKernelGGL(conj_kernel, grid, block, 0, stream, x, W, out);
}